// Round 1
// baseline (408.782 us; speedup 1.0000x reference)
//
#include <hip/hip_runtime.h>

#define NB    32
#define CIN   64
#define COUT  128
#define HH    56
#define WW    56
#define NPIX  (NB*HH*WW)          // 100352 samples per channel
#define BN_EPSF 1e-5f

// ---------------- zero the stats accumulators (re-poisoned each call) --------
__global__ void zero_sums(float* g) {
    g[threadIdx.x] = 0.0f;        // 256 floats: gsum[128] + gsq[128]
}

// ---------------- assemble block-diagonal weights -> wT[ic][kh][kw][oc] ------
// w[o][col] = w_blocks[p][q][i][j], o=p*8+i, col=q*8+j, col = ic*9+kh*3+kw
__global__ void assemble_w(const float* __restrict__ wb, float* __restrict__ wT) {
    int idx = blockIdx.x * 256 + threadIdx.x;
    if (idx >= 576 * 128) return;
    int col = idx >> 7, oc = idx & 127;
    int p = oc >> 3, i = oc & 7, q = col >> 3, j = col & 7;
    wT[idx] = wb[((p * 72 + q) * 8 + i) * 8 + j];
}

// ---------------- direct conv + per-channel partial sums ---------------------
// block: one image n, 8x8 spatial tile, all 128 oc. 256 threads.
// thread: ocg = tid&15 -> 8 oc, pxg = tid>>4 -> 4 consecutive px in one row.
__global__ __launch_bounds__(256) void conv_bn_partial(
    const float* __restrict__ x, const float* __restrict__ wT,
    float* __restrict__ y, float* __restrict__ gsum, float* __restrict__ gsq)
{
    __shared__ float x_tile[8 * 10 * 10];    // 3200 B
    __shared__ float w_tile[8 * 9 * 128];    // 36864 B
    __shared__ float red[2 * COUT];          // 1024 B

    int b  = blockIdx.x;
    int n  = b / 49;
    int t  = b % 49;
    int h0 = (t / 7) * 8;
    int w0 = (t % 7) * 8;
    int tid = threadIdx.x;
    int ocg = tid & 15;
    int pxg = tid >> 4;
    int py  = pxg >> 1;
    int cx0 = (pxg & 1) * 4;
    int oc0 = ocg * 8;

    float acc[4][8];
    #pragma unroll
    for (int i = 0; i < 4; ++i)
        #pragma unroll
        for (int j = 0; j < 8; ++j) acc[i][j] = 0.0f;

    for (int chunk = 0; chunk < 8; ++chunk) {
        int ic0 = chunk * 8;
        __syncthreads();
        // stage x: 8 ic x 10x10 halo tile, zero-padded at borders
        for (int idx = tid; idx < 800; idx += 256) {
            int i = idx / 100, rem = idx % 100;
            int r = rem / 10, c = rem % 10;
            int gh = h0 - 1 + r, gw = w0 - 1 + c;
            float v = 0.0f;
            if (gh >= 0 && gh < HH && gw >= 0 && gw < WW)
                v = x[((n * CIN + ic0 + i) * HH + gh) * WW + gw];
            x_tile[idx] = v;
        }
        // stage weights: contiguous 9216 floats for this ic-chunk
        const float4* wsrc = (const float4*)(wT + ic0 * 9 * 128);
        float4* wdst = (float4*)w_tile;
        for (int idx = tid; idx < 9216 / 4; idx += 256)
            wdst[idx] = wsrc[idx];
        __syncthreads();

        #pragma unroll
        for (int ic = 0; ic < 8; ++ic) {
            #pragma unroll
            for (int kh = 0; kh < 3; ++kh) {
                float xr[6];
                const float* xrow = &x_tile[ic * 100 + (py + kh) * 10 + cx0];
                #pragma unroll
                for (int tt = 0; tt < 6; ++tt) xr[tt] = xrow[tt];
                #pragma unroll
                for (int kw = 0; kw < 3; ++kw) {
                    const float* wrow = &w_tile[((ic * 3 + kh) * 3 + kw) * 128 + oc0];
                    float wv[8];
                    #pragma unroll
                    for (int j = 0; j < 8; ++j) wv[j] = wrow[j];
                    #pragma unroll
                    for (int j = 0; j < 8; ++j)
                        #pragma unroll
                        for (int i = 0; i < 4; ++i)
                            acc[i][j] = fmaf(xr[kw + i], wv[j], acc[i][j]);
                }
            }
        }
    }

    // write raw y (pre-BN) to d_out
    #pragma unroll
    for (int j = 0; j < 8; ++j) {
        int oc = oc0 + j;
        float4 v = make_float4(acc[0][j], acc[1][j], acc[2][j], acc[3][j]);
        *(float4*)&y[((n * COUT + oc) * HH + (h0 + py)) * WW + (w0 + cx0)] = v;
    }

    // per-block per-channel partial sums -> global atomics
    if (tid < COUT) { red[tid] = 0.0f; red[COUT + tid] = 0.0f; }
    __syncthreads();
    #pragma unroll
    for (int j = 0; j < 8; ++j) {
        float s = 0.0f, sq = 0.0f;
        #pragma unroll
        for (int i = 0; i < 4; ++i) { s += acc[i][j]; sq += acc[i][j] * acc[i][j]; }
        atomicAdd(&red[oc0 + j], s);
        atomicAdd(&red[COUT + oc0 + j], sq);
    }
    __syncthreads();
    if (tid < COUT) {
        atomicAdd(&gsum[tid], red[tid]);
        atomicAdd(&gsq[tid],  red[COUT + tid]);
    }
}

// ---------------- BN scale/shift from accumulated stats ----------------------
__global__ void bn_finalize(const float* __restrict__ gsum, const float* __restrict__ gsq,
                            const float* __restrict__ gamma, const float* __restrict__ beta,
                            float* __restrict__ scale, float* __restrict__ shift)
{
    int c = threadIdx.x;
    float mean = gsum[c] * (1.0f / NPIX);
    float var  = gsq[c]  * (1.0f / NPIX) - mean * mean;
    float inv  = gamma[c] / sqrtf(var + BN_EPSF);
    scale[c] = inv;
    shift[c] = beta[c] - mean * inv;
}

// ---------------- apply BN + clip, in-place on d_out, float4 -----------------
__global__ __launch_bounds__(256) void bn_apply(float* __restrict__ y,
        const float* __restrict__ scale, const float* __restrict__ shift)
{
    const int total4 = NB * COUT * HH * WW / 4;   // 3211264
    int idx = blockIdx.x * blockDim.x + threadIdx.x;
    int stride = gridDim.x * blockDim.x;
    for (int i4 = idx; i4 < total4; i4 += stride) {
        int c = (i4 / 784) & 127;                 // 784 float4 per channel-plane
        float sc = scale[c], sh = shift[c];
        float4 v = ((float4*)y)[i4];
        v.x = fminf(fmaxf(fmaf(v.x, sc, sh), 0.0f), 6.0f);
        v.y = fminf(fmaxf(fmaf(v.y, sc, sh), 0.0f), 6.0f);
        v.z = fminf(fmaxf(fmaf(v.z, sc, sh), 0.0f), 6.0f);
        v.w = fminf(fmaxf(fmaf(v.w, sc, sh), 0.0f), 6.0f);
        ((float4*)y)[i4] = v;
    }
}

extern "C" void kernel_launch(void* const* d_in, const int* in_sizes, int n_in,
                              void* d_out, int out_size, void* d_ws, size_t ws_size,
                              hipStream_t stream) {
    const float* x     = (const float*)d_in[0];
    const float* wb    = (const float*)d_in[1];
    const float* gamma = (const float*)d_in[2];
    const float* beta  = (const float*)d_in[3];
    float* y  = (float*)d_out;
    float* ws = (float*)d_ws;

    float* wT    = ws;              // 73728 floats
    float* gsum  = ws + 73728;      // 128
    float* gsq   = gsum + 128;      // 128
    float* scale = gsq + 128;       // 128
    float* shift = scale + 128;     // 128

    zero_sums<<<1, 256, 0, stream>>>(gsum);
    assemble_w<<<(576 * 128 + 255) / 256, 256, 0, stream>>>(wb, wT);
    conv_bn_partial<<<NB * 49, 256, 0, stream>>>(x, wT, y, gsum, gsq);
    bn_finalize<<<1, COUT, 0, stream>>>(gsum, gsq, gamma, beta, scale, shift);
    bn_apply<<<2048, 256, 0, stream>>>(y, scale, shift);
}

// Round 3
// 202.674 us; speedup vs baseline: 2.0169x; 2.0169x over previous
//
#include <hip/hip_runtime.h>

#define NB    32
#define CIN   64
#define COUT  128
#define HH    56
#define WW    56
#define NPIX  (NB*HH*WW)
#define BN_EPSF 1e-5f

typedef __bf16 bf16x8 __attribute__((ext_vector_type(8)));
typedef float  f32x4  __attribute__((ext_vector_type(4)));
typedef unsigned short u16x8 __attribute__((ext_vector_type(8)));

// ---------------- zero the stats accumulators --------------------------------
__global__ void zero_sums(float* g) {
    g[threadIdx.x] = 0.0f;        // 256 floats: gsum[128] + gsq[128]
}

// ------- assemble block-diag weights -> split bf16 hi/lo, [tap][half][oc][32]
__global__ void assemble_w(const float* __restrict__ wb,
                           __bf16* __restrict__ whi, __bf16* __restrict__ wlo) {
    int idx = blockIdx.x * 256 + threadIdx.x;
    if (idx >= 576 * 128) return;
    int col = idx >> 7, oc = idx & 127;          // col = ic*9 + kh*3 + kw
    int p = oc >> 3, i = oc & 7, q = col >> 3, j = col & 7;
    float v = wb[((p * 72 + q) * 8 + i) * 8 + j];
    int ic = col / 9, tap = col % 9;
    int dst = ((tap * 2 + (ic >> 5)) * 128 + oc) * 32 + (ic & 31);
    __bf16 hi = (__bf16)v;
    whi[dst] = hi;
    wlo[dst] = (__bf16)(v - (float)hi);
}

// ---------------- MFMA implicit-GEMM conv + per-channel partial sums ---------
// block: image n, 14x8 spatial tile (M=112), all 128 oc. 4 waves x 32 oc.
__global__ __launch_bounds__(256, 2) void conv_mfma(
    const float* __restrict__ x, const __bf16* __restrict__ whi,
    const __bf16* __restrict__ wlo, float* __restrict__ y,
    float* __restrict__ gsum, float* __restrict__ gsq)
{
    __shared__ __bf16 xs_hi[160 * 72];   // [16 rows x 10 cols][64 ic, pad 72]
    __shared__ __bf16 xs_lo[160 * 72];
    __shared__ __bf16 wb_hi[128 * 40];   // [128 oc][32 ic, pad 40]
    __shared__ __bf16 wb_lo[128 * 40];
    __shared__ float  red[256];

    int b = blockIdx.x;
    int n = b / 28, t = b % 28;
    int h0 = (t / 7) * 14, w0 = (t % 7) * 8;
    int tid  = threadIdx.x;
    int lane = tid & 63, wid = tid >> 6;
    int l15 = lane & 15, l4 = lane >> 4;
    int oc0 = wid * 32;

    // ---- stage x halo once: fp32 -> (hi, lo) bf16, transposed [px][ic] ----
    const float* xn = x + n * CIN * HH * WW;
    for (int idx = tid; idx < 64 * 160; idx += 256) {
        int ic = idx / 160, px = idx - ic * 160;
        int r = px / 10, c = px - r * 10;
        int gh = h0 - 1 + r, gw = w0 - 1 + c;
        float v = 0.0f;
        if ((unsigned)gh < 56u && (unsigned)gw < 56u)
            v = xn[(ic * HH + gh) * WW + gw];
        __bf16 hi = (__bf16)v;
        xs_hi[px * 72 + ic] = hi;
        xs_lo[px * 72 + ic] = (__bf16)(v - (float)hi);
    }

    f32x4 acc[7][2] = {};

    for (int tap = 0; tap < 9; ++tap) {
        int kh = tap / 3, kw = tap - kh * 3;
        for (int half = 0; half < 2; ++half) {
            __syncthreads();
            {   // stage w chunk: 128 oc x 32 ic (hi & lo) = 512 chunks of 8 bf16
                int base = (tap * 2 + half) * 128 * 32;
                for (int c = tid; c < 512; c += 256) {
                    int oc = c >> 2, part = c & 3;
                    int src = base + oc * 32 + part * 8;
                    int dst = oc * 40 + part * 8;
                    *(u16x8*)&wb_hi[dst] = *(const u16x8*)&whi[src];
                    *(u16x8*)&wb_lo[dst] = *(const u16x8*)&wlo[src];
                }
            }
            __syncthreads();

            int koffA = half * 32 + l4 * 8;
            int koffB = l4 * 8;
            bf16x8 bh0 = *(const bf16x8*)&wb_hi[(oc0 +      l15) * 40 + koffB];
            bf16x8 bh1 = *(const bf16x8*)&wb_hi[(oc0 + 16 + l15) * 40 + koffB];
            bf16x8 bl0 = *(const bf16x8*)&wb_lo[(oc0 +      l15) * 40 + koffB];
            bf16x8 bl1 = *(const bf16x8*)&wb_lo[(oc0 + 16 + l15) * 40 + koffB];

            #pragma unroll
            for (int mt = 0; mt < 7; ++mt) {
                int px = mt * 16 + l15;
                int R  = ((px >> 3) + kh) * 10 + (px & 7) + kw;
                int ae = R * 72 + koffA;
                bf16x8 ah = *(const bf16x8*)&xs_hi[ae];
                bf16x8 al = *(const bf16x8*)&xs_lo[ae];
                acc[mt][0] = __builtin_amdgcn_mfma_f32_16x16x32_bf16(ah, bh0, acc[mt][0], 0, 0, 0);
                acc[mt][1] = __builtin_amdgcn_mfma_f32_16x16x32_bf16(ah, bh1, acc[mt][1], 0, 0, 0);
                acc[mt][0] = __builtin_amdgcn_mfma_f32_16x16x32_bf16(ah, bl0, acc[mt][0], 0, 0, 0);
                acc[mt][1] = __builtin_amdgcn_mfma_f32_16x16x32_bf16(ah, bl1, acc[mt][1], 0, 0, 0);
                acc[mt][0] = __builtin_amdgcn_mfma_f32_16x16x32_bf16(al, bh0, acc[mt][0], 0, 0, 0);
                acc[mt][1] = __builtin_amdgcn_mfma_f32_16x16x32_bf16(al, bh1, acc[mt][1], 0, 0, 0);
            }
        }
    }

    // ---- write raw y (pre-BN): float4 per (mt,nt) ----
    // C/D layout: col(oc_local)=lane&15, row(px)=(lane>>4)*4 + reg  [m89]
    float* yn = y + n * COUT * HH * WW;
    int pyb = l4 >> 1;                 // row offset within mt's 2-row pair
    int gwo = w0 + (l4 & 1) * 4;       // 4-aligned col group
    #pragma unroll
    for (int mt = 0; mt < 7; ++mt) {
        int gh = h0 + mt * 2 + pyb;
        #pragma unroll
        for (int nt = 0; nt < 2; ++nt) {
            int oc = oc0 + nt * 16 + l15;
            *(float4*)&yn[(oc * HH + gh) * WW + gwo] = *(float4*)&acc[mt][nt];
        }
    }

    // ---- per-channel partial stats: reduce across the 4 k-group lanes ----
    #pragma unroll
    for (int nt = 0; nt < 2; ++nt) {
        float s = 0.0f, sq = 0.0f;
        #pragma unroll
        for (int mt = 0; mt < 7; ++mt)
            #pragma unroll
            for (int r = 0; r < 4; ++r) {
                float v = acc[mt][nt][r];
                s += v; sq += v * v;
            }
        s  += __shfl_xor(s, 16, 64);  s  += __shfl_xor(s, 32, 64);
        sq += __shfl_xor(sq, 16, 64); sq += __shfl_xor(sq, 32, 64);
        if (l4 == 0) {                 // unique writer per oc -> plain store
            int oc = oc0 + nt * 16 + l15;
            red[oc] = s; red[128 + oc] = sq;
        }
    }
    __syncthreads();
    if (tid < 128) {
        atomicAdd(&gsum[tid], red[tid]);
        atomicAdd(&gsq[tid],  red[128 + tid]);
    }
}

// ---------------- BN scale/shift from accumulated stats ----------------------
__global__ void bn_finalize(const float* __restrict__ gsum, const float* __restrict__ gsq,
                            const float* __restrict__ gamma, const float* __restrict__ beta,
                            float* __restrict__ scale, float* __restrict__ shift)
{
    int c = threadIdx.x;
    float mean = gsum[c] * (1.0f / NPIX);
    float var  = gsq[c]  * (1.0f / NPIX) - mean * mean;
    float inv  = gamma[c] / sqrtf(var + BN_EPSF);
    scale[c] = inv;
    shift[c] = beta[c] - mean * inv;
}

// ---------------- apply BN + clip, in-place on d_out, float4 -----------------
__global__ __launch_bounds__(256) void bn_apply(float* __restrict__ y,
        const float* __restrict__ scale, const float* __restrict__ shift)
{
    const int total4 = NB * COUT * HH * WW / 4;   // 3211264
    int idx = blockIdx.x * blockDim.x + threadIdx.x;
    int stride = gridDim.x * blockDim.x;
    for (int i4 = idx; i4 < total4; i4 += stride) {
        int c = (i4 / 784) & 127;
        float sc = scale[c], sh = shift[c];
        float4 v = ((float4*)y)[i4];
        v.x = fminf(fmaxf(fmaf(v.x, sc, sh), 0.0f), 6.0f);
        v.y = fminf(fmaxf(fmaf(v.y, sc, sh), 0.0f), 6.0f);
        v.z = fminf(fmaxf(fmaf(v.z, sc, sh), 0.0f), 6.0f);
        v.w = fminf(fmaxf(fmaf(v.w, sc, sh), 0.0f), 6.0f);
        ((float4*)y)[i4] = v;
    }
}

extern "C" void kernel_launch(void* const* d_in, const int* in_sizes, int n_in,
                              void* d_out, int out_size, void* d_ws, size_t ws_size,
                              hipStream_t stream) {
    const float* x     = (const float*)d_in[0];
    const float* wb    = (const float*)d_in[1];
    const float* gamma = (const float*)d_in[2];
    const float* beta  = (const float*)d_in[3];
    float* y = (float*)d_out;

    __bf16* whi = (__bf16*)d_ws;                 // 73728 bf16
    __bf16* wlo = whi + 73728;                   // 73728 bf16
    float* stats = (float*)(wlo + 73728);        // byte offset 294912
    float* gsum  = stats;
    float* gsq   = gsum + 128;
    float* scale = gsq + 128;
    float* shift = scale + 128;

    zero_sums<<<1, 256, 0, stream>>>(gsum);
    assemble_w<<<(576 * 128 + 255) / 256, 256, 0, stream>>>(wb, whi, wlo);
    conv_mfma<<<NB * 28, 256, 0, stream>>>(x, whi, wlo, y, gsum, gsq);
    bn_finalize<<<1, COUT, 0, stream>>>(gsum, gsq, gamma, beta, scale, shift);
    bn_apply<<<2048, 256, 0, stream>>>(y, scale, shift);
}

// Round 4
// 163.164 us; speedup vs baseline: 2.5053x; 1.2421x over previous
//
#include <hip/hip_runtime.h>

#define NB    32
#define CIN   64
#define COUT  128
#define HH    56
#define WW    56
#define NPIX  (NB*HH*WW)
#define BN_EPSF 1e-5f

typedef __bf16 bf16x8 __attribute__((ext_vector_type(8)));
typedef float  f32x4  __attribute__((ext_vector_type(4)));
typedef unsigned short u16x8 __attribute__((ext_vector_type(8)));

// ---------------- zero the stats accumulators --------------------------------
__global__ void zero_sums(float* g) {
    g[threadIdx.x] = 0.0f;        // 256 floats: gsum[128] + gsq[128]
}

// ------- assemble block-diag weights -> split bf16 hi/lo, [tap][half][oc][32]
__global__ void assemble_w(const float* __restrict__ wb,
                           __bf16* __restrict__ whi, __bf16* __restrict__ wlo) {
    int idx = blockIdx.x * 256 + threadIdx.x;
    if (idx >= 576 * 128) return;
    int col = idx >> 7, oc = idx & 127;          // col = ic*9 + kh*3 + kw
    int p = oc >> 3, i = oc & 7, q = col >> 3, j = col & 7;
    float v = wb[((p * 72 + q) * 8 + i) * 8 + j];
    int ic = col / 9, tap = col % 9;
    int dst = ((tap * 2 + (ic >> 5)) * 128 + oc) * 32 + (ic & 31);
    __bf16 hi = (__bf16)v;
    whi[dst] = hi;
    wlo[dst] = (__bf16)(v - (float)hi);
}

// ---------------- MFMA implicit-GEMM conv, barrier-free K-loop ---------------
// block: image n, 14x8 spatial tile (M=112), all 128 oc. 4 waves x 32 oc.
// x halo staged once in LDS (hi/lo bf16, XOR-swizzled 16B chunks);
// B-fragments read directly from global (L2-resident, 288 KB total).
__global__ __launch_bounds__(256, 4) void conv_mfma(
    const float* __restrict__ x, const __bf16* __restrict__ whi,
    const __bf16* __restrict__ wlo, float* __restrict__ y,
    float* __restrict__ gsum, float* __restrict__ gsq)
{
    __shared__ __bf16 xs_hi[160 * 64];   // [halo px 16x10][64 ic], swizzled
    __shared__ __bf16 xs_lo[160 * 64];

    int b = blockIdx.x;
    int n = b / 28, t = b % 28;
    int h0 = (t / 7) * 14, w0 = (t % 7) * 8;
    int tid  = threadIdx.x;
    int lane = tid & 63, wid = tid >> 6;
    int l15 = lane & 15, l4 = lane >> 4;
    int oc0 = wid * 32;

    // ---- stage x halo: thread = (chunk c, px); 8 coalesced global loads,
    // one 16B hi + one 16B lo LDS write at swizzled chunk (c ^ (px&7)) ----
    const float* xn = x + n * CIN * HH * WW;
    for (int u = tid; u < 1280; u += 256) {
        int c = u / 160, px = u - c * 160;
        int r = px / 10, cc = px - r * 10;
        int gh = h0 - 1 + r, gw = w0 - 1 + cc;
        bool ok = ((unsigned)gh < 56u) & ((unsigned)gw < 56u);
        const float* src = xn + (c * 8) * (HH * WW) + gh * WW + gw;
        bf16x8 hi, lo;
        #pragma unroll
        for (int j = 0; j < 8; ++j) {
            float v = ok ? src[j * HH * WW] : 0.0f;
            __bf16 h = (__bf16)v;
            hi[j] = h;
            lo[j] = (__bf16)(v - (float)h);
        }
        int dst = px * 64 + ((c ^ (px & 7)) * 8);
        *(bf16x8*)&xs_hi[dst] = hi;
        *(bf16x8*)&xs_lo[dst] = lo;
    }
    __syncthreads();

    f32x4 acc[7][2] = {};

    for (int tap = 0; tap < 9; ++tap) {
        int kh = tap / 3, kw = tap - kh * 3;
        #pragma unroll
        for (int half = 0; half < 2; ++half) {
            const __bf16* bh = whi + ((tap * 2 + half) * 128) * 32;
            const __bf16* bl = wlo + ((tap * 2 + half) * 128) * 32;
            bf16x8 bh0 = *(const bf16x8*)&bh[(oc0 +      l15) * 32 + l4 * 8];
            bf16x8 bh1 = *(const bf16x8*)&bh[(oc0 + 16 + l15) * 32 + l4 * 8];
            bf16x8 bl0 = *(const bf16x8*)&bl[(oc0 +      l15) * 32 + l4 * 8];
            bf16x8 bl1 = *(const bf16x8*)&bl[(oc0 + 16 + l15) * 32 + l4 * 8];
            int cbase = half * 4 + l4;

            #pragma unroll
            for (int mt = 0; mt < 7; ++mt) {
                int px = mt * 16 + l15;
                int R  = ((px >> 3) + kh) * 10 + (px & 7) + kw;
                int ae = R * 64 + ((cbase ^ (R & 7)) * 8);
                bf16x8 ah = *(const bf16x8*)&xs_hi[ae];
                bf16x8 al = *(const bf16x8*)&xs_lo[ae];
                acc[mt][0] = __builtin_amdgcn_mfma_f32_16x16x32_bf16(ah, bh0, acc[mt][0], 0, 0, 0);
                acc[mt][1] = __builtin_amdgcn_mfma_f32_16x16x32_bf16(ah, bh1, acc[mt][1], 0, 0, 0);
                acc[mt][0] = __builtin_amdgcn_mfma_f32_16x16x32_bf16(ah, bl0, acc[mt][0], 0, 0, 0);
                acc[mt][1] = __builtin_amdgcn_mfma_f32_16x16x32_bf16(ah, bl1, acc[mt][1], 0, 0, 0);
                acc[mt][0] = __builtin_amdgcn_mfma_f32_16x16x32_bf16(al, bh0, acc[mt][0], 0, 0, 0);
                acc[mt][1] = __builtin_amdgcn_mfma_f32_16x16x32_bf16(al, bh1, acc[mt][1], 0, 0, 0);
            }
        }
    }

    // ---- write raw y (pre-BN): float4 per (mt,nt) ----
    // C/D layout: col(oc_local)=lane&15, row(px)=(lane>>4)*4 + reg  [m89]
    float* yn = y + n * COUT * HH * WW;
    int pyb = l4 >> 1;
    int gwo = w0 + (l4 & 1) * 4;
    #pragma unroll
    for (int mt = 0; mt < 7; ++mt) {
        int gh = h0 + mt * 2 + pyb;
        #pragma unroll
        for (int nt = 0; nt < 2; ++nt) {
            int oc = oc0 + nt * 16 + l15;
            *(float4*)&yn[(oc * HH + gh) * WW + gwo] = *(float4*)&acc[mt][nt];
        }
    }

    // ---- per-channel partial stats; red aliases xs (all xs reads done) ----
    float* red = (float*)xs_hi;
    __syncthreads();
    #pragma unroll
    for (int nt = 0; nt < 2; ++nt) {
        float s = 0.0f, sq = 0.0f;
        #pragma unroll
        for (int mt = 0; mt < 7; ++mt)
            #pragma unroll
            for (int r = 0; r < 4; ++r) {
                float v = acc[mt][nt][r];
                s += v; sq += v * v;
            }
        s  += __shfl_xor(s, 16, 64);  s  += __shfl_xor(s, 32, 64);
        sq += __shfl_xor(sq, 16, 64); sq += __shfl_xor(sq, 32, 64);
        if (l4 == 0) {
            int oc = oc0 + nt * 16 + l15;
            red[oc] = s; red[128 + oc] = sq;
        }
    }
    __syncthreads();
    if (tid < 128) {
        atomicAdd(&gsum[tid], red[tid]);
        atomicAdd(&gsq[tid],  red[128 + tid]);
    }
}

// ---------------- BN scale/shift from accumulated stats ----------------------
__global__ void bn_finalize(const float* __restrict__ gsum, const float* __restrict__ gsq,
                            const float* __restrict__ gamma, const float* __restrict__ beta,
                            float* __restrict__ scale, float* __restrict__ shift)
{
    int c = threadIdx.x;
    float mean = gsum[c] * (1.0f / NPIX);
    float var  = gsq[c]  * (1.0f / NPIX) - mean * mean;
    float inv  = gamma[c] / sqrtf(var + BN_EPSF);
    scale[c] = inv;
    shift[c] = beta[c] - mean * inv;
}

// ---------------- apply BN + clip, in-place on d_out, float4 -----------------
__global__ __launch_bounds__(256) void bn_apply(float* __restrict__ y,
        const float* __restrict__ scale, const float* __restrict__ shift)
{
    const int total4 = NB * COUT * HH * WW / 4;   // 3211264
    int idx = blockIdx.x * blockDim.x + threadIdx.x;
    int stride = gridDim.x * blockDim.x;
    for (int i4 = idx; i4 < total4; i4 += stride) {
        int c = (i4 / 784) & 127;
        float sc = scale[c], sh = shift[c];
        float4 v = ((float4*)y)[i4];
        v.x = fminf(fmaxf(fmaf(v.x, sc, sh), 0.0f), 6.0f);
        v.y = fminf(fmaxf(fmaf(v.y, sc, sh), 0.0f), 6.0f);
        v.z = fminf(fmaxf(fmaf(v.z, sc, sh), 0.0f), 6.0f);
        v.w = fminf(fmaxf(fmaf(v.w, sc, sh), 0.0f), 6.0f);
        ((float4*)y)[i4] = v;
    }
}

extern "C" void kernel_launch(void* const* d_in, const int* in_sizes, int n_in,
                              void* d_out, int out_size, void* d_ws, size_t ws_size,
                              hipStream_t stream) {
    const float* x     = (const float*)d_in[0];
    const float* wb    = (const float*)d_in[1];
    const float* gamma = (const float*)d_in[2];
    const float* beta  = (const float*)d_in[3];
    float* y = (float*)d_out;

    __bf16* whi = (__bf16*)d_ws;                 // 73728 bf16
    __bf16* wlo = whi + 73728;                   // 73728 bf16
    float* gsum  = (float*)(wlo + 73728);
    float* gsq   = gsum + 128;
    float* scale = gsq + 128;
    float* shift = scale + 128;

    zero_sums<<<1, 256, 0, stream>>>(gsum);
    assemble_w<<<(576 * 128 + 255) / 256, 256, 0, stream>>>(wb, whi, wlo);
    conv_mfma<<<NB * 28, 256, 0, stream>>>(x, whi, wlo, y, gsum, gsq);
    bn_finalize<<<1, COUT, 0, stream>>>(gsum, gsq, gamma, beta, scale, shift);
    bn_apply<<<2048, 256, 0, stream>>>(y, scale, shift);
}